// Round 5
// baseline (422.857 us; speedup 1.0000x reference)
//
#include <hip/hip_runtime.h>
#include <hip/hip_fp16.h>

// GCNEncoder: 2-layer GCN. Bucket partition + per-bucket refine -> per-node CSR,
// fp16 message tables (fp32 accumulate), transform2 fused into pull1.
// N=200000, E=6.4M, dims 32->32->16.

#define BN 256          // nodes per bucket
#define NB_MAX 1024     // max buckets
#define CHUNK 4096      // edges per partition block
#define CAP 12288       // refine LDS staging capacity (mean run 8184, +45 sigma)

__global__ __launch_bounds__(256) void zero_buckets(int* bucket_cnt, int nb) {
    int i = blockIdx.x * 256 + threadIdx.x;
    if (i < nb) bucket_cnt[i] = 0;
}

// P1: global bucket histogram
__global__ __launch_bounds__(256) void hist_kernel(const int* __restrict__ dst, int E,
                                                   int* __restrict__ bucket_cnt, int nb) {
    __shared__ int hist[NB_MAX];
    for (int b = threadIdx.x; b < nb; b += 256) hist[b] = 0;
    __syncthreads();
    int e0 = blockIdx.x * CHUNK;
    for (int k = 0; k < CHUNK / 256; ++k) {
        int e = e0 + k * 256 + threadIdx.x;
        if (e < E) atomicAdd(&hist[dst[e] >> 8], 1);
    }
    __syncthreads();
    for (int b = threadIdx.x; b < nb; b += 256) {
        int c = hist[b];
        if (c) atomicAdd(&bucket_cnt[b], c);
    }
}

// P2: single-block exclusive scan
__global__ __launch_bounds__(256) void scan_kernel(const int* __restrict__ bucket_cnt,
                                                   int* __restrict__ bucket_base,
                                                   int* __restrict__ gcursor, int nb) {
    __shared__ int wsum[4];
    int tid = threadIdx.x, lane = tid & 63, wid = tid >> 6;
    int s0 = tid * 4;
    int local[4]; int part = 0;
    for (int j = 0; j < 4; ++j) { int b = s0 + j; local[j] = (b < nb) ? bucket_cnt[b] : 0; part += local[j]; }
    int v = part;
    for (int o = 1; o < 64; o <<= 1) { int t = __shfl_up(v, o); if (lane >= o) v += t; }
    if (lane == 63) wsum[wid] = v;
    __syncthreads();
    int woff = 0;
    for (int w = 0; w < wid; ++w) woff += wsum[w];
    int run = woff + v - part;
    for (int j = 0; j < 4; ++j) {
        int b = s0 + j;
        if (b < nb) { bucket_base[b] = run; gcursor[b] = run; run += local[j]; }
    }
}

// P3: partition into per-bucket runs. Packed word: (src<<8)|dst_local.
__global__ __launch_bounds__(256) void partition_kernel(
    const int* __restrict__ src, const int* __restrict__ dst, int E,
    int* __restrict__ gcursor, unsigned int* __restrict__ ebuf, int nb) {
    __shared__ int hist[NB_MAX];
    __shared__ int scan_[NB_MAX];
    __shared__ int cur[NB_MAX];
    __shared__ int gbase[NB_MAX];
    __shared__ unsigned int sword[CHUNK];
    __shared__ unsigned short sbkt[CHUNK];
    __shared__ int wsum[4];
    __shared__ int totv;
    int tid = threadIdx.x;
    int e0 = blockIdx.x * CHUNK;
    int myd[16], mys[16];
    for (int k = 0; k < 16; ++k) {
        int e = e0 + k * 256 + tid;
        myd[k] = (e < E) ? dst[e] : -1;
        mys[k] = (e < E) ? src[e] : 0;
    }
    for (int b = tid; b < nb; b += 256) hist[b] = 0;
    __syncthreads();
    for (int k = 0; k < 16; ++k) if (myd[k] >= 0) atomicAdd(&hist[myd[k] >> 8], 1);
    __syncthreads();
    {   // block exclusive scan of hist
        int lane = tid & 63, wid = tid >> 6;
        int s0 = tid * 4;
        int local[4]; int part = 0;
        for (int j = 0; j < 4; ++j) { int b = s0 + j; local[j] = (b < nb) ? hist[b] : 0; part += local[j]; }
        int v = part;
        for (int o = 1; o < 64; o <<= 1) { int t = __shfl_up(v, o); if (lane >= o) v += t; }
        if (lane == 63) wsum[wid] = v;
        __syncthreads();
        int woff = 0;
        for (int w = 0; w < wid; ++w) woff += wsum[w];
        int run = woff + v - part;
        for (int j = 0; j < 4; ++j) {
            int b = s0 + j;
            if (b < nb) { scan_[b] = run; cur[b] = run; run += local[j]; }
        }
        if (tid == 255) totv = run;
    }
    __syncthreads();
    for (int k = 0; k < 16; ++k) {
        if (myd[k] >= 0) {
            int b = myd[k] >> 8;
            int r = atomicAdd(&cur[b], 1);
            sword[r] = ((unsigned)mys[k] << 8) | (unsigned)(myd[k] & 255);
            sbkt[r] = (unsigned short)b;
        }
    }
    __syncthreads();
    for (int b = tid; b < nb; b += 256) {
        int c = cur[b] - scan_[b];
        if (c) gbase[b] = atomicAdd(&gcursor[b], c);
    }
    __syncthreads();
    int tv = totv;
    for (int i = tid; i < tv; i += 256) {
        int b = sbkt[i];
        ebuf[gbase[b] + (i - scan_[b])] = sword[i];
    }
}

// P4: refine -> per-node CSR (in place), start/deg/dinv
__global__ __launch_bounds__(256) void refine_kernel(
    unsigned int* __restrict__ ebuf, const int* __restrict__ bucket_base,
    const int* __restrict__ bucket_cnt,
    int* __restrict__ node_start, int* __restrict__ node_deg,
    float* __restrict__ dinv, int n) {
    __shared__ int cnt[BN];
    __shared__ int cur[BN];
    __shared__ int wsum[4];
    __shared__ int ssrc[CAP];
    int b = blockIdx.x, tid = threadIdx.x;
    int s = bucket_base[b], len = bucket_cnt[b];
    cnt[tid] = 0;
    __syncthreads();
    for (int i = tid; i < len; i += 256) atomicAdd(&cnt[ebuf[s + i] & 255u], 1);
    __syncthreads();
    int v = cnt[tid];
    int inc = v;
    int lane = tid & 63, wid = tid >> 6;
    for (int o = 1; o < 64; o <<= 1) { int t = __shfl_up(inc, o); if (lane >= o) inc += t; }
    if (lane == 63) wsum[wid] = inc;
    __syncthreads();
    int woff = 0;
    for (int w = 0; w < wid; ++w) woff += wsum[w];
    int excl = woff + inc - v;
    cur[tid] = excl;
    int node = b * BN + tid;
    if (node < n) {
        node_start[node] = s + excl;
        node_deg[node] = v;
        dinv[node] = rsqrtf((float)v + 1.0f);
    }
    __syncthreads();
    if (len <= CAP) {
        for (int i = tid; i < len; i += 256) {
            unsigned int w = ebuf[s + i];
            int r = atomicAdd(&cur[w & 255u], 1);
            ssrc[r] = (int)(w >> 8);
        }
        __syncthreads();
        for (int i = tid; i < len; i += 256) ebuf[s + i] = (unsigned int)ssrc[i];
    } else {
        for (int i = tid; i < len; i += 256) {
            unsigned int w = ebuf[s + i];
            int r = atomicAdd(&cur[w & 255u], 1);
            ebuf[s + r] = (w >> 8);
        }
    }
}

// hws1 = fp16( (x @ W1) * dinv[row] )
__global__ __launch_bounds__(256) void transform1(
    const float* __restrict__ x, const float* __restrict__ W1,
    const float* __restrict__ dinv, __half* __restrict__ hws1, int n) {
    __shared__ float sW[32 * 32];
    __shared__ float sx[8 * 32];
    int tid = threadIdx.x;
    for (int i = tid; i < 1024; i += 256) sW[i] = W1[i];
    int node0 = blockIdx.x * 8;
    int node_ld = node0 + tid / 32;
    sx[tid] = (node_ld < n) ? x[node_ld * 32 + (tid & 31)] : 0.0f;
    __syncthreads();
    int local = tid >> 5;
    int f = tid & 31;
    int node = node0 + local;
    if (node >= n) return;
    float acc = 0.0f;
#pragma unroll
    for (int k = 0; k < 32; ++k) acc += sx[local * 32 + k] * sW[k * 32 + f];
    hws1[(size_t)node * 32 + f] = __float2half(acc * dinv[node]);
}

// Fused: h1row = relu(b1 + dinv*agg(hws1)); hws2 = fp16(h1row @ W2 * dinv)
// 4 lanes per node; lane l owns h1 feats [8l,8l+8), writes hws2 feats [4l,4l+4).
__global__ __launch_bounds__(256) void pull1_fused(
    const int* __restrict__ node_start, const int* __restrict__ node_deg,
    const unsigned int* __restrict__ ecsr, const float* __restrict__ dinv,
    const __half* __restrict__ hws1, const float* __restrict__ b1,
    const float* __restrict__ W2, __half* __restrict__ hws2, int n) {
    __shared__ float sW2[32 * 17];
    __shared__ float sb1[32];
    int tid = threadIdx.x;
    for (int i = tid; i < 512; i += 256) sW2[(i >> 4) * 17 + (i & 15)] = W2[i];
    if (tid < 32) sb1[tid] = b1[tid];
    __syncthreads();
    int g = tid >> 2;
    int l = tid & 3;
    int d = blockIdx.x * 64 + g;
    if (d >= n) return;
    int b = node_start[d], len = node_deg[d];
    const float4* H = (const float4*)hws1;  // row = 4x float4 (32 halves)
    float acc[8];
    {
        float4 raw = H[(size_t)d * 4 + l];  // self-loop term
        const __half2* h2 = (const __half2*)&raw;
#pragma unroll
        for (int q = 0; q < 4; ++q) {
            float2 f2 = __half22float2(h2[q]);
            acc[2 * q] = f2.x; acc[2 * q + 1] = f2.y;
        }
    }
    int j = 0;
    for (; j + 2 <= len; j += 2) {
        int s0 = (int)ecsr[b + j], s1 = (int)ecsr[b + j + 1];
        float4 r0 = H[(size_t)s0 * 4 + l];
        float4 r1 = H[(size_t)s1 * 4 + l];
        const __half2* a0 = (const __half2*)&r0;
        const __half2* a1 = (const __half2*)&r1;
#pragma unroll
        for (int q = 0; q < 4; ++q) {
            float2 f0 = __half22float2(a0[q]);
            float2 f1 = __half22float2(a1[q]);
            acc[2 * q]     += f0.x + f1.x;
            acc[2 * q + 1] += f0.y + f1.y;
        }
    }
    if (j < len) {
        float4 r0 = H[(size_t)(int)ecsr[b + j] * 4 + l];
        const __half2* a0 = (const __half2*)&r0;
#pragma unroll
        for (int q = 0; q < 4; ++q) {
            float2 f0 = __half22float2(a0[q]);
            acc[2 * q]     += f0.x;
            acc[2 * q + 1] += f0.y;
        }
    }
    float di = dinv[d];
    float h1v[8];
#pragma unroll
    for (int q = 0; q < 8; ++q)
        h1v[q] = fmaxf(sb1[8 * l + q] + di * acc[q], 0.0f);
    // partial products for all 16 outputs over my 8 k's
    float p[16];
#pragma unroll
    for (int f = 0; f < 16; ++f) p[f] = 0.0f;
#pragma unroll
    for (int q = 0; q < 8; ++q) {
        float hv = h1v[q];
        const float* wrow = &sW2[(8 * l + q) * 17];
#pragma unroll
        for (int f = 0; f < 16; ++f) p[f] += hv * wrow[f];
    }
    // reduce across the 4-lane group
#pragma unroll
    for (int f = 0; f < 16; ++f) {
        p[f] += __shfl_xor(p[f], 1);
        p[f] += __shfl_xor(p[f], 2);
    }
    __half2 o0 = __floats2half2_rn(p[4 * l] * di, p[4 * l + 1] * di);
    __half2 o1 = __floats2half2_rn(p[4 * l + 2] * di, p[4 * l + 3] * di);
    __half2* HW2 = (__half2*)hws2;
    HW2[(size_t)d * 8 + 2 * l]     = o0;
    HW2[(size_t)d * 8 + 2 * l + 1] = o1;
}

// out = b2 + dinv[d]*(hws2[d] + sum hws2[src]); 2 lanes per node, fp16 gathers
__global__ __launch_bounds__(256) void pull2(
    const int* __restrict__ node_start, const int* __restrict__ node_deg,
    const unsigned int* __restrict__ ecsr, const float* __restrict__ dinv,
    const __half* __restrict__ hws2, const float* __restrict__ b2,
    float* __restrict__ out, int n) {
    int g = threadIdx.x >> 1;
    int l = threadIdx.x & 1;
    int d = blockIdx.x * 128 + g;
    if (d >= n) return;
    int b = node_start[d], len = node_deg[d];
    const float4* H = (const float4*)hws2;  // row = 2x float4 (16 halves)
    float acc[8];
    {
        float4 raw = H[(size_t)d * 2 + l];  // self-loop term
        const __half2* h2 = (const __half2*)&raw;
#pragma unroll
        for (int q = 0; q < 4; ++q) {
            float2 f2 = __half22float2(h2[q]);
            acc[2 * q] = f2.x; acc[2 * q + 1] = f2.y;
        }
    }
    int j = 0;
    for (; j + 2 <= len; j += 2) {
        int s0 = (int)ecsr[b + j], s1 = (int)ecsr[b + j + 1];
        float4 r0 = H[(size_t)s0 * 2 + l];
        float4 r1 = H[(size_t)s1 * 2 + l];
        const __half2* a0 = (const __half2*)&r0;
        const __half2* a1 = (const __half2*)&r1;
#pragma unroll
        for (int q = 0; q < 4; ++q) {
            float2 f0 = __half22float2(a0[q]);
            float2 f1 = __half22float2(a1[q]);
            acc[2 * q]     += f0.x + f1.x;
            acc[2 * q + 1] += f0.y + f1.y;
        }
    }
    if (j < len) {
        float4 r0 = H[(size_t)(int)ecsr[b + j] * 2 + l];
        const __half2* a0 = (const __half2*)&r0;
#pragma unroll
        for (int q = 0; q < 4; ++q) {
            float2 f0 = __half22float2(a0[q]);
            acc[2 * q]     += f0.x;
            acc[2 * q + 1] += f0.y;
        }
    }
    float di = dinv[d];
    float4 o0, o1;
    o0.x = b2[8 * l + 0] + di * acc[0];
    o0.y = b2[8 * l + 1] + di * acc[1];
    o0.z = b2[8 * l + 2] + di * acc[2];
    o0.w = b2[8 * l + 3] + di * acc[3];
    o1.x = b2[8 * l + 4] + di * acc[4];
    o1.y = b2[8 * l + 5] + di * acc[5];
    o1.z = b2[8 * l + 6] + di * acc[6];
    o1.w = b2[8 * l + 7] + di * acc[7];
    float4* O = (float4*)out;
    O[(size_t)d * 4 + 2 * l]     = o0;
    O[(size_t)d * 4 + 2 * l + 1] = o1;
}

extern "C" void kernel_launch(void* const* d_in, const int* in_sizes, int n_in,
                              void* d_out, int out_size, void* d_ws, size_t ws_size,
                              hipStream_t stream) {
    const float* x  = (const float*)d_in[0];
    const int*   ei = (const int*)d_in[1];
    const float* W1 = (const float*)d_in[2];
    const float* b1 = (const float*)d_in[3];
    const float* W2 = (const float*)d_in[4];
    const float* b2 = (const float*)d_in[5];

    int n = in_sizes[0] / 32;  // 200000
    int E = in_sizes[1] / 2;   // 6400000
    const int* src = ei;
    const int* dst = ei + E;

    int nb = (n + BN - 1) / BN;  // 782

    char* w = (char*)d_ws;
    int*   bucket_cnt  = (int*)w;    w += (size_t)NB_MAX * 4;
    int*   bucket_base = (int*)w;    w += (size_t)NB_MAX * 4;
    int*   gcursor     = (int*)w;    w += (size_t)NB_MAX * 4;
    float* dinv        = (float*)w;  w += (size_t)n * 4;
    int*   node_start  = (int*)w;    w += (size_t)n * 4;
    int*   node_deg    = (int*)w;    w += (size_t)n * 4;
    unsigned int* ebuf = (unsigned int*)w; w += (size_t)E * 4;
    __half* hws1       = (__half*)w; w += (size_t)n * 32 * 2;
    __half* hws2       = (__half*)w; w += (size_t)n * 16 * 2;
    float* out         = (float*)d_out;

    int nchunks = (E + CHUNK - 1) / CHUNK;

    zero_buckets    <<<(nb + 255) / 256, 256, 0, stream>>>(bucket_cnt, nb);
    hist_kernel     <<<nchunks, 256, 0, stream>>>(dst, E, bucket_cnt, nb);
    scan_kernel     <<<1, 256, 0, stream>>>(bucket_cnt, bucket_base, gcursor, nb);
    partition_kernel<<<nchunks, 256, 0, stream>>>(src, dst, E, gcursor, ebuf, nb);
    refine_kernel   <<<nb, 256, 0, stream>>>(ebuf, bucket_base, bucket_cnt,
                                             node_start, node_deg, dinv, n);

    transform1 <<<(n + 7) / 8, 256, 0, stream>>>(x, W1, dinv, hws1, n);
    pull1_fused<<<(n + 63) / 64, 256, 0, stream>>>(node_start, node_deg, ebuf, dinv,
                                                   hws1, b1, W2, hws2, n);
    pull2      <<<(n + 127) / 128, 256, 0, stream>>>(node_start, node_deg, ebuf, dinv,
                                                     hws2, b2, out, n);
}